// Round 10
// baseline (12314.597 us; speedup 1.0000x reference)
//
#include <hip/hip_runtime.h>
#include <hip/hip_fp16.h>
#include <math.h>

#define SEQ    8192
#define EMBD   256
#define HD     128
#define GATES  512
#define NTAGS  14
#define TAG_START 12
#define TAG_STOP  13
#define NEGV   (-10000.0f)

// ---- ws layout (float offsets) ----
static constexpr size_t OFF_X     = 0;                               // [SEQ][EMBD]
static constexpr size_t OFF_WT    = OFF_X + (size_t)SEQ * EMBD;      // [EMBD][1024]
static constexpr size_t OFF_BSUM  = OFF_WT + (size_t)EMBD * 1024;    // [1024]
static constexpr size_t OFF_GF    = OFF_BSUM + 1024;                 // [SEQ+4][GATES] quad-layout
static constexpr size_t OFF_GB    = OFF_GF + (size_t)(SEQ + 4) * GATES;
static constexpr size_t OFF_HF    = OFF_GB + (size_t)(SEQ + 4) * GATES; // [SEQ][HD]
static constexpr size_t OFF_HB    = OFF_HF + (size_t)SEQ * HD;          // [SEQ][HD]
static constexpr size_t OFF_FEATS = OFF_HB + (size_t)SEQ * HD;          // [SEQ+8][16]
static constexpr size_t OFF_BP    = OFF_FEATS + (size_t)(SEQ + 8) * 16; // uchar[SEQ][16]
static constexpr size_t OFF_AC    = OFF_BP + (size_t)SEQ * 16 / 4;      // [64][256] chunk matrices
static constexpr size_t OFF_FVB   = OFF_AC + (size_t)64 * 256;          // [64][16] boundary fv
static constexpr size_t OFF_SB    = OFF_FVB + 1024;                     // [4] best-tag etc.

#define LOG2E  1.4426950408889634f
#define LOG2E2 2.8853900817779268f

typedef _Float16 half2_t __attribute__((ext_vector_type(2)));

__device__ __forceinline__ float fast_rcp(float x) { return __builtin_amdgcn_rcpf(x); }
__device__ __forceinline__ float bcast_lane(float x, int lane) {
  return __int_as_float(__builtin_amdgcn_readlane(__float_as_int(x), lane));
}
__device__ __forceinline__ float max3f(float a, float b, float c) {
  return fmaxf(fmaxf(a, b), c);   // -> v_max3_f32
}
__device__ __forceinline__ float max14(const float s[NTAGS]) {
  float m0 = max3f(s[0], s[1], s[2]);
  float m1 = max3f(s[3], s[4], s[5]);
  float m2 = max3f(s[6], s[7], s[8]);
  float m3 = max3f(s[9], s[10], s[11]);
  float m4 = fmaxf(s[12], s[13]);
  return max3f(max3f(m0, m1, m2), m3, m4);
}
template<int CTRL>
__device__ __forceinline__ float quad_dpp(float x) {
  int xi = __float_as_int(x);
  int r = __builtin_amdgcn_update_dpp(xi, xi, CTRL, 0xF, 0xF, false);
  return __int_as_float(r);
}

// f32-accumulating f16 dot2 (v_dot2_f32_f16) with safe fallback
__device__ __forceinline__ float dot2acc(half2_t a, half2_t b, float c) {
#if __has_builtin(__builtin_amdgcn_fdot2)
  return __builtin_amdgcn_fdot2(a, b, c, false);
#else
  return fmaf((float)a[0], (float)b[0], fmaf((float)a[1], (float)b[1], c));
#endif
}

// sigmoid / tanh via native exp2+rcp (passed absmax=0 in r4..r9)
__device__ __forceinline__ float sigf(float x) {
  return fast_rcp(1.0f + exp2f(x * -LOG2E));
}
__device__ __forceinline__ float tanhf_(float x) {
  return fmaf(2.0f, fast_rcp(1.0f + exp2f(x * -LOG2E2)), -1.0f);
}

// barrier that waits LDS only (lgkmcnt), NOT vmcnt -> global prefetch stays in flight
__device__ __forceinline__ void lds_barrier() {
  __builtin_amdgcn_sched_barrier(0);
  asm volatile("s_waitcnt lgkmcnt(0)" ::: "memory");
  __builtin_amdgcn_s_barrier();
  __builtin_amdgcn_sched_barrier(0);
}

// argmax over 14 values, first-index tie-break (matches jnp.argmax)
__device__ __forceinline__ void argmax14(const float s[NTAGS], float& bv, int& bi) {
#define MRG(va, ia, vb, ib, vo, io) { bool c_ = (vb) > (va); (vo) = c_ ? (vb) : (va); (io) = c_ ? (ib) : (ia); }
  float v0, v1, v2, v3, v4, v5, v6; int i0, i1, i2, i3, i4, i5, i6;
  MRG(s[0], 0, s[1], 1, v0, i0); MRG(s[2], 2, s[3], 3, v1, i1);
  MRG(s[4], 4, s[5], 5, v2, i2); MRG(s[6], 6, s[7], 7, v3, i3);
  MRG(s[8], 8, s[9], 9, v4, i4); MRG(s[10], 10, s[11], 11, v5, i5);
  MRG(s[12], 12, s[13], 13, v6, i6);
  float w0, w1, w2; int j0, j1, j2;
  MRG(v0, i0, v1, i1, w0, j0); MRG(v2, i2, v3, i3, w1, j1); MRG(v4, i4, v5, i5, w2, j2);
  float x0, x1; int y0, y1;
  MRG(w0, j0, w1, j1, x0, y0); MRG(w2, j2, v6, i6, x1, y1);
  MRG(x0, y0, x1, y1, bv, bi);
#undef MRG
}

// ---------------- prep: W transpose-pack (quad-permuted cols) + bias sums ----------------
__global__ void prep_k(const float* __restrict__ wihf, const float* __restrict__ wihb,
                       const float* __restrict__ bihf, const float* __restrict__ bhhf,
                       const float* __restrict__ bihb, const float* __restrict__ bhhb,
                       float* __restrict__ WT, float* __restrict__ bsum) {
  if (blockIdx.x < 1024) {
    int e = blockIdx.x * 256 + threadIdx.x;     // e over [EMBD*1024)
    int k = e >> 10, c = e & 1023;
    int cq = c & 511;
    int src = (cq & 3) * HD + (cq >> 2);
    WT[e] = (c < GATES) ? wihf[(size_t)src * EMBD + k] : wihb[(size_t)src * EMBD + k];
  } else {
    for (int i = 0; i < 4; ++i) {
      int c = threadIdx.x + i * 256;
      int cq = c & 511;
      int src = (cq & 3) * HD + (cq >> 2);
      bsum[c] = (c < GATES) ? (bihf[src] + bhhf[src]) : (bihb[src] + bhhb[src]);
    }
  }
}

// ---------------- embedding gather ----------------
__global__ void gather_k(const int* __restrict__ sent, const float* __restrict__ emb,
                         float* __restrict__ X) {
  int t = blockIdx.x;
  int row = sent[t];
  ((float4*)(X + (size_t)t * EMBD))[threadIdx.x] =
      ((const float4*)(emb + (size_t)row * EMBD))[threadIdx.x];
}

// ---------------- input-projection GEMM: G = X @ W^T + bsum ----------------
__global__ __launch_bounds__(256) void gemm_k(const float* __restrict__ X,
                                              const float* __restrict__ WT,
                                              const float* __restrict__ bsum,
                                              float* __restrict__ Gf, float* __restrict__ Gb) {
  __shared__ __align__(16) float As[32][68];   // [k][m], padded stride
  __shared__ __align__(16) float Bs[32][64];   // [k][n]
  const int tid = threadIdx.x;
  const int cb = blockIdx.x * 64;              // 0..960
  const int tb = blockIdx.y * 64;
  const bool flip = (cb >= GATES);
  const int ty = tid >> 4, tx = tid & 15;
  float acc[4][4] = {};

  const int r  = tid >> 2;                     // A-stage: row 0..63
  const int kq = (tid & 3) * 8;                // 8 k's
  const int kB = tid >> 3;                     // B-stage: k 0..31
  const int n8 = (tid & 7) * 8;

  const int trow = tb + r;
  const int src = flip ? (SEQ - 1 - trow) : trow;

  for (int k0 = 0; k0 < EMBD; k0 += 32) {
    const float* xp = X + (size_t)src * EMBD + k0 + kq;
    float4 xa = *(const float4*)xp;
    float4 xb = *(const float4*)(xp + 4);
    As[kq + 0][r] = xa.x; As[kq + 1][r] = xa.y; As[kq + 2][r] = xa.z; As[kq + 3][r] = xa.w;
    As[kq + 4][r] = xb.x; As[kq + 5][r] = xb.y; As[kq + 6][r] = xb.z; As[kq + 7][r] = xb.w;
    const float* wp = WT + (size_t)(k0 + kB) * 1024 + cb + n8;
    *(float4*)&Bs[kB][n8]     = *(const float4*)wp;
    *(float4*)&Bs[kB][n8 + 4] = *(const float4*)(wp + 4);
    __syncthreads();
    #pragma unroll
    for (int k = 0; k < 32; ++k) {
      float4 av = *(const float4*)&As[k][ty * 4];
      float4 bv = *(const float4*)&Bs[k][tx * 4];
      acc[0][0] = fmaf(av.x, bv.x, acc[0][0]); acc[0][1] = fmaf(av.x, bv.y, acc[0][1]);
      acc[0][2] = fmaf(av.x, bv.z, acc[0][2]); acc[0][3] = fmaf(av.x, bv.w, acc[0][3]);
      acc[1][0] = fmaf(av.y, bv.x, acc[1][0]); acc[1][1] = fmaf(av.y, bv.y, acc[1][1]);
      acc[1][2] = fmaf(av.y, bv.z, acc[1][2]); acc[1][3] = fmaf(av.y, bv.w, acc[1][3]);
      acc[2][0] = fmaf(av.z, bv.x, acc[2][0]); acc[2][1] = fmaf(av.z, bv.y, acc[2][1]);
      acc[2][2] = fmaf(av.z, bv.z, acc[2][2]); acc[2][3] = fmaf(av.z, bv.w, acc[2][3]);
      acc[3][0] = fmaf(av.w, bv.x, acc[3][0]); acc[3][1] = fmaf(av.w, bv.y, acc[3][1]);
      acc[3][2] = fmaf(av.w, bv.z, acc[3][2]); acc[3][3] = fmaf(av.w, bv.w, acc[3][3]);
    }
    __syncthreads();
  }
  float4 bz = *(const float4*)&bsum[cb + tx * 4];
  #pragma unroll
  for (int mm = 0; mm < 4; ++mm) {
    int t = tb + ty * 4 + mm;
    float4 v = { acc[mm][0] + bz.x, acc[mm][1] + bz.y, acc[mm][2] + bz.z, acc[mm][3] + bz.w };
    if (!flip) *(float4*)&Gf[(size_t)t * GATES + cb + tx * 4] = v;
    else       *(float4*)&Gb[(size_t)t * GATES + (cb - GATES) + tx * 4] = v;
  }
}

// ---------------- serial LSTM recurrence: ONE block, BOTH directions per thread ----------
// 256 threads, thread tt -> hidden j = tt>>1, k-half s = tt&1; each thread carries
// BOTH directions' state (weights, cell, G prefetch). The two independent dep
// chains interleave in-thread, so each chain's LDS/transcendental bubbles are
// filled by the other chain's issue (unlike the failed r7 wave-level merge whose
// lockstep barrier aligned all bubbles). One lgkmcnt-only barrier per step.
// VGPR ~300 (weights 256) -- fine at 1 wave/SIMD (cap ~512, no-spill to ~450).
__global__ __launch_bounds__(256, 1) void lstm_k(
    const float* __restrict__ whhf, const float* __restrict__ whhb,
    const float* __restrict__ Gf, const float* __restrict__ Gb,
    float* __restrict__ HF, float* __restrict__ HB) {
  const int tt = threadIdx.x;
  const int j = tt >> 1;        // hidden index 0..127
  const int s = tt & 1;         // k-half 0..1
  const bool s0 = (s == 0);

  // weights for both directions: k-half [64s, 64s+64) of row (gate*HD + j)
  half2_t wf[4][32], wb[4][32];
  #pragma unroll
  for (int gi = 0; gi < 4; ++gi) {
    const float* wrf = whhf + (size_t)(gi * HD + j) * HD + s * 64;
    const float* wrb = whhb + (size_t)(gi * HD + j) * HD + s * 64;
    #pragma unroll
    for (int kk = 0; kk < 32; ++kk) {
      half2_t w; w[0] = (_Float16)wrf[2 * kk]; w[1] = (_Float16)wrf[2 * kk + 1];
      wf[gi][kk] = w;
      half2_t v; v[0] = (_Float16)wrb[2 * kk]; v[1] = (_Float16)wrb[2 * kk + 1];
      wb[gi][kk] = v;
    }
  }

  __shared__ __align__(16) __half hAf[HD], hBf[HD], hAb[HD], hBb[HD];
  if (tt < HD) { hAf[tt] = __float2half_rn(0.0f); hAb[tt] = __float2half_rn(0.0f); }
  float cf = 0.0f, cbw = 0.0f;

  // depth-2 float4 G prefetch per direction (A = even steps, B = odd steps)
  const float* gpAf = Gf + 4 * j;
  const float* gpBf = Gf + GATES + 4 * j;
  const float* gpAb = Gb + 4 * j;
  const float* gpBb = Gb + GATES + 4 * j;
  float4 gAf = *(const float4*)gpAf; gpAf += 2 * GATES;
  float4 gBf = *(const float4*)gpBf; gpBf += 2 * GATES;
  float4 gAb = *(const float4*)gpAb; gpAb += 2 * GATES;
  float4 gBb = *(const float4*)gpBb; gpBb += 2 * GATES;

  float* houtf = HF + j;                               // ascending
  float* houtb = HB + (size_t)(SEQ - 1) * HD + j;      // descending
  const int hoff = s << 6;

  lds_barrier();

  auto step = [&](const __half* hrdF, __half* hwrF, float4& gsF, const float*& gpF,
                  const __half* hrdB, __half* hwrB, float4& gsB, const float*& gpB) {
    float4 gcf = gsF; gsF = *(const float4*)gpF; gpF += 2 * GATES;
    float4 gcb = gsB; gsB = *(const float4*)gpB; gpB += 2 * GATES;

    const float4* hpf = (const float4*)(hrdF + hoff);
    const float4* hpb = (const float4*)(hrdB + hoff);
    float af[4][2] = {}, ab[4][2] = {};
    #pragma unroll
    for (int i = 0; i < 8; ++i) {
      float4 hvf = hpf[i];
      float4 hvb = hpb[i];
      const half2_t* hf2 = (const half2_t*)&hvf;
      const half2_t* hb2 = (const half2_t*)&hvb;
      #pragma unroll
      for (int m = 0; m < 4; ++m) {
        const int kk = i * 4 + m;
        af[0][kk & 1] = dot2acc(wf[0][kk], hf2[m], af[0][kk & 1]);
        af[1][kk & 1] = dot2acc(wf[1][kk], hf2[m], af[1][kk & 1]);
        af[2][kk & 1] = dot2acc(wf[2][kk], hf2[m], af[2][kk & 1]);
        af[3][kk & 1] = dot2acc(wf[3][kk], hf2[m], af[3][kk & 1]);
        ab[0][kk & 1] = dot2acc(wb[0][kk], hb2[m], ab[0][kk & 1]);
        ab[1][kk & 1] = dot2acc(wb[1][kk], hb2[m], ab[1][kk & 1]);
        ab[2][kk & 1] = dot2acc(wb[2][kk], hb2[m], ab[2][kk & 1]);
        ab[3][kk & 1] = dot2acc(wb[3][kk], hb2[m], ab[3][kk & 1]);
      }
    }
    float pf0 = af[0][0] + af[0][1], pf1 = af[1][0] + af[1][1];
    float pf2 = af[2][0] + af[2][1], pf3 = af[3][0] + af[3][1];
    float pb0 = ab[0][0] + ab[0][1], pb1 = ab[1][0] + ab[1][1];
    float pb2 = ab[2][0] + ab[2][1], pb3 = ab[3][0] + ab[3][1];

    // one DPP xor1 round completes each sum in both pair-lanes
    pf0 += quad_dpp<0xB1>(pf0); pf1 += quad_dpp<0xB1>(pf1);
    pf2 += quad_dpp<0xB1>(pf2); pf3 += quad_dpp<0xB1>(pf3);
    pb0 += quad_dpp<0xB1>(pb0); pb1 += quad_dpp<0xB1>(pb1);
    pb2 += quad_dpp<0xB1>(pb2); pb3 += quad_dpp<0xB1>(pb3);

    float if_ = sigf(pf0 + gcf.x);
    float ib_ = sigf(pb0 + gcb.x);
    float ff_ = sigf(pf1 + gcf.y);
    float fb_ = sigf(pb1 + gcb.y);
    float gf_ = tanhf_(pf2 + gcf.z);
    float gb_ = tanhf_(pb2 + gcb.z);
    float of_ = sigf(pf3 + gcf.w);
    float ob_ = sigf(pb3 + gcb.w);
    cf  = fmaf(ff_, cf,  if_ * gf_);
    cbw = fmaf(fb_, cbw, ib_ * gb_);
    float hjf = of_ * tanhf_(cf);
    float hjb = ob_ * tanhf_(cbw);
    if (s0) {
      hwrF[j] = __float2half_rn(hjf); *houtf = hjf;
      hwrB[j] = __float2half_rn(hjb); *houtb = hjb;
    }
    houtf += HD; houtb -= HD;
    lds_barrier();   // the ONLY barrier per step (lgkmcnt-only)
  };

  for (int t = 0; t < SEQ; t += 2) {
    step(hAf, hBf, gAf, gpAf, hAb, hBb, gAb, gpAb);
    step(hBf, hAf, gBf, gpBf, hBb, hAb, gBb, gpBb);
  }
}

// ---------------- tag-space projection: feats = [hf|hb] @ w_tag^T + b_tag ----------------
__global__ void feats_k(const float* __restrict__ HF, const float* __restrict__ HB,
                        const float* __restrict__ wtag, const float* __restrict__ btag,
                        float* __restrict__ feats) {
  const int t = blockIdx.x, l = threadIdx.x;   // 64 lanes
  float2 a = ((const float2*)(HF + (size_t)t * HD))[l];
  float2 b = ((const float2*)(HB + (size_t)t * HD))[l];
  float p[NTAGS];
  #pragma unroll
  for (int n = 0; n < NTAGS; ++n) {
    const float* wr = wtag + (size_t)n * 256;
    float2 w0 = ((const float2*)wr)[l];
    float2 w1 = ((const float2*)(wr + HD))[l];
    p[n] = a.x * w0.x + a.y * w0.y + b.x * w1.x + b.y * w1.y;
  }
  #pragma unroll
  for (int n = 0; n < NTAGS; ++n) {
    float v = p[n];
    for (int off = 32; off > 0; off >>= 1) v += __shfl_down(v, off);
    if (l == 0) feats[(size_t)t * 16 + n] = v + btag[n];
  }
}

// ---------------- Viterbi, parallel-scan formulation (measured ~300us total) ----------
__global__ __launch_bounds__(256) void vit_a(const float* __restrict__ feats,
                                             const float* __restrict__ trans,
                                             float* __restrict__ Ac) {
  const int c = blockIdx.x;
  const int tid = threadIdx.x;
  const int n = tid % NTAGS, p = tid / NTAGS;
  const bool act = tid < NTAGS * NTAGS;
  __shared__ __align__(16) float fl[128][16];   // chunk feats
  __shared__ float Ab[2][NTAGS][17];            // stride-17: conflict-light

  const float4* fsrc = (const float4*)(feats + (size_t)c * 128 * 16);
  #pragma unroll
  for (int i = 0; i < 2; ++i)
    ((float4*)&fl[0][0])[tid + i * 256] = fsrc[tid + i * 256];

  float Tr[NTAGS];
  if (act) {
    #pragma unroll
    for (int qq = 0; qq < NTAGS; ++qq) Tr[qq] = trans[n * NTAGS + qq];
  }
  __syncthreads();
  if (act) Ab[0][n][p] = Tr[p] + fl[0][n];      // first step: A = M_{t0}
  __syncthreads();

  int cur = 0;
  for (int tl = 1; tl < 128; ++tl) {
    if (act) {
      float s[NTAGS];
      #pragma unroll
      for (int qq = 0; qq < NTAGS; ++qq) s[qq] = Tr[qq] + Ab[cur][qq][p];
      Ab[cur ^ 1][n][p] = max14(s) + fl[tl][n];
    }
    __syncthreads();
    cur ^= 1;
  }
  if (act) Ac[(size_t)c * 256 + n * 16 + p] = Ab[cur][n][p];
}

__global__ void vit_b(const float* __restrict__ trans, const float* __restrict__ Ac,
                      float* __restrict__ fvb, float* __restrict__ out,
                      float* __restrict__ sb) {
  const int n = threadIdx.x;
  const bool act = n < NTAGS;
  float fv = (n == TAG_START) ? 0.0f : NEGV;
  for (int c = 0; c < 64; ++c) {
    if (act) fvb[c * 16 + n] = fv;
    float Ar[NTAGS];
    #pragma unroll
    for (int p = 0; p < NTAGS; ++p) Ar[p] = act ? Ac[(size_t)c * 256 + n * 16 + p] : NEGV;
    float s[NTAGS];
    #pragma unroll
    for (int p = 0; p < NTAGS; ++p) s[p] = Ar[p] + bcast_lane(fv, p);
    float nf = max14(s);
    fv = act ? nf : NEGV;
  }
  float tn = fv + (act ? trans[TAG_STOP * NTAGS + n] : NEGV);
  float tv[NTAGS];
  #pragma unroll
  for (int p = 0; p < NTAGS; ++p) tv[p] = bcast_lane(tn, p);
  if (n == 0) {
    float bv; int bi;
    argmax14(tv, bv, bi);
    out[0] = bv;                       // score
    ((int*)sb)[0] = bi;                // best terminal tag
  }
}

__global__ void vit_c(const float* __restrict__ feats, const float* __restrict__ trans,
                      const float* __restrict__ fvb, unsigned char* __restrict__ bpg) {
  const int c = blockIdx.x;
  const int n = threadIdx.x;
  const bool act = n < NTAGS;
  float Tn[NTAGS];
  #pragma unroll
  for (int p = 0; p < NTAGS; ++p) Tn[p] = act ? trans[n * NTAGS + p] : 0.0f;
  float fv = act ? fvb[c * 16 + n] : NEGV;
  const int t0 = c * 128;

  float fbuf[8];
  #pragma unroll
  for (int u = 0; u < 8; ++u) fbuf[u] = act ? feats[(size_t)(t0 + u) * 16 + n] : 0.0f;

  for (int tb = 0; tb < 128; tb += 8) {
    #pragma unroll
    for (int u = 0; u < 8; ++u) {
      const int t = t0 + tb + u;
      float ftc = fbuf[u];
      fbuf[u] = act ? feats[(size_t)(t + 8) * 16 + n] : 0.0f;   // padded rows
      float s[NTAGS];
      #pragma unroll
      for (int p = 0; p < NTAGS; ++p) s[p] = bcast_lane(fv, p) + Tn[p];
      float bv = max14(s);
      fv = bv + ftc;
      int bi = 13;
      #pragma unroll
      for (int p = 12; p >= 0; --p) bi = (s[p] == bv) ? p : bi;
      if (act) bpg[(size_t)t * 16 + n] = (unsigned char)bi;
    }
  }
}

__global__ __launch_bounds__(1024) void vit_d(const unsigned char* __restrict__ bpg,
                                              const float* __restrict__ sb,
                                              float* __restrict__ out) {
  __shared__ int sh_M[64 * 16];
  __shared__ int sh_B[64];
  const int tid = threadIdx.x;
  {                               // phase B: compose 128-step backpointer maps per chunk
    const int c = tid >> 4, k = tid & 15;
    if (c >= 1 && c < 64 && k < NTAGS) {
      int x = k;
      for (int i = 127; i >= 0; --i) x = bpg[((size_t)(c * 128 + i)) * 16 + x];
      sh_M[c * 16 + k] = x;
    }
  }
  __syncthreads();
  if (tid == 0) {                 // phase C: serial walk over 64 chunk boundaries
    int b = ((const int*)sb)[0];
    sh_B[63] = b;
    for (int c = 63; c >= 1; --c) { b = sh_M[c * 16 + b]; sh_B[c - 1] = b; }
  }
  __syncthreads();
  if (tid < 64) {                 // phase D: chunks re-walk in parallel, emit path
    const int c = tid;
    int x = sh_B[c];
    out[1 + c * 128 + 127] = (float)x;
    for (int i = 127; i >= 1; --i) {
      x = bpg[((size_t)(c * 128 + i)) * 16 + x];
      out[1 + c * 128 + i - 1] = (float)x;
    }
  }
}

extern "C" void kernel_launch(void* const* d_in, const int* in_sizes, int n_in,
                              void* d_out, int out_size, void* d_ws, size_t ws_size,
                              hipStream_t stream) {
  (void)in_sizes; (void)n_in; (void)out_size; (void)ws_size;
  const int*   sent = (const int*)d_in[0];
  const float* emb  = (const float*)d_in[1];
  const float* wihf = (const float*)d_in[2];
  const float* whhf = (const float*)d_in[3];
  const float* bihf = (const float*)d_in[4];
  const float* bhhf = (const float*)d_in[5];
  const float* wihb = (const float*)d_in[6];
  const float* whhb = (const float*)d_in[7];
  const float* bihb = (const float*)d_in[8];
  const float* bhhb = (const float*)d_in[9];
  const float* wtag = (const float*)d_in[10];
  const float* btag = (const float*)d_in[11];
  const float* trans = (const float*)d_in[12];

  float* ws = (float*)d_ws;
  float* X    = ws + OFF_X;
  float* WT   = ws + OFF_WT;
  float* BS   = ws + OFF_BSUM;
  float* Gf   = ws + OFF_GF;
  float* Gb   = ws + OFF_GB;
  float* HF   = ws + OFF_HF;
  float* HB   = ws + OFF_HB;
  float* FE   = ws + OFF_FEATS;
  unsigned char* bpg = (unsigned char*)(ws + OFF_BP);
  float* AC   = ws + OFF_AC;
  float* FVB  = ws + OFF_FVB;
  float* SB   = ws + OFF_SB;
  float* out = (float*)d_out;

  prep_k<<<1025, 256, 0, stream>>>(wihf, wihb, bihf, bhhf, bihb, bhhb, WT, BS);
  gather_k<<<SEQ, 64, 0, stream>>>(sent, emb, X);
  gemm_k<<<dim3(16, 128), 256, 0, stream>>>(X, WT, BS, Gf, Gb);
  lstm_k<<<1, 256, 0, stream>>>(whhf, whhb, Gf, Gb, HF, HB);
  feats_k<<<SEQ, 64, 0, stream>>>(HF, HB, wtag, btag, FE);
  vit_a<<<64, 256, 0, stream>>>(FE, trans, AC);
  vit_b<<<1, 64, 0, stream>>>(trans, AC, FVB, out, SB);
  vit_c<<<64, 64, 0, stream>>>(FE, trans, FVB, bpg);
  vit_d<<<1, 1024, 0, stream>>>(bpg, SB, out);
}